// Round 4
// baseline (465.588 us; speedup 1.0000x reference)
//
#include <hip/hip_runtime.h>
#include <stdint.h>

// CPRLinear: out = x[:, ci] @ dequant(W).T + bias
// B=256, IN=OUT=8192; W_high (8192x2048 int32, tile 128), W_low (8192x6144).
// R3 diagnosis: latency-bound (all pipes 10-20%, occ 21%, 2 waves/SIMD).
// R4: A-operand in registers (1-step-ahead reg dbuf, private -> off the
// barrier path), LDS only for W tile (8KB dbuf) + scales -> 16KB LDS,
// KSPLIT=8 -> 1024 blocks = 4 blocks/CU (16 waves/CU). Bare-asm lgkmcnt
// (m201 pattern, no memory clobber); all VMEM compiler-counted.

#define IN_DIM 8192
#define OUT_DIM 8192
#define BDIM 256
#define NH 2048
#define NL 6144
#define BN 64
#define BK 32

// LDS (16KB): W dbuf 2x4096 @0; SC @8192; ZS @12288 (<=4KB each)
#define WOFF 0
#define SCOFF 8192
#define ZSOFF 12288

typedef __bf16 bf16x8 __attribute__((ext_vector_type(8)));
typedef float f32x4 __attribute__((ext_vector_type(4)));

__device__ __forceinline__ unsigned short bfbits(float f) {
  union { float f; unsigned int u; } v; v.f = f;
  unsigned int u = v.u;
  u += 0x7fffu + ((u >> 16) & 1u);   // RNE
  return (unsigned short)(u >> 16);
}
__device__ __forceinline__ unsigned int pk2(float a, float b) {
  return (unsigned int)bfbits(a) | ((unsigned int)bfbits(b) << 16);
}

// ---------------- gather + bf16 convert: xp[b][k] = bf16(x[b][ci[k]]) ------
__global__ void gather_k(const float* __restrict__ x,
                         const int* __restrict__ ci,
                         unsigned short* __restrict__ xp) {
  int i4 = blockIdx.x * blockDim.x + threadIdx.x;   // 0..524287
  int b = i4 >> 11;                                  // row (2048 quads/row)
  int k4 = (i4 & 2047) << 2;
  int4 c = *(const int4*)(ci + k4);
  const float* xr = x + (size_t)b * IN_DIM;
  uint2 st;
  st.x = pk2(xr[c.x], xr[c.y]);
  st.y = pk2(xr[c.z], xr[c.w]);
  *(uint2*)(xp + (size_t)b * IN_DIM + k4) = st;
}

// ---------------- GEMM ----------------------------------------------------
// Grid (128, KSPL). Block 256 thr = 4 waves; wave wv owns rows wv*64..+63,
// cols n0..n0+63. A from global (reg dbuf, 1 step ahead); W int32 -> reg
// (2 steps ahead) -> dequant -> LDS dbuf; per-step: 1 raw barrier + lgkm(0).
template<int KSPL>
__global__ __launch_bounds__(256, 4)
void gemm_k(const unsigned short* __restrict__ xp,
            const int* __restrict__ Whq, const int* __restrict__ Wlq,
            const float* __restrict__ sh, const float* __restrict__ zh,
            const float* __restrict__ sl, const float* __restrict__ zl,
            const float* __restrict__ bias,
            float* __restrict__ outp,
            int use_atomic)
{
  constexpr int KSEG = IN_DIM / KSPL;     // 1024 (K8) / 2048 (K4)
  constexpr int NSTEP = KSEG / BK;        // 32 / 64
  constexpr int NT = KSEG / 128;          // scale tiles per segment: 8 / 16
  constexpr int HSEG = NH / KSEG;         // high-region segments: 2 / 1

  __shared__ char smem[16384];
  const int t = threadIdx.x;
  const int lane = t & 63;
  const int wv = t >> 6;
  const int kh = blockIdx.y;
  const int n0 = blockIdx.x * BN;
  const int l15 = lane & 15;
  const int g4 = lane >> 4;
  const bool hi = (kh < HSEG);

  // W staging: thread t -> col = t>>2 (of 64), k-chunk wm = t&3 (8 ints)
  const int wcol = t >> 2;
  const int wm = t & 3;
  const int* wb0 = hi ? (Whq + (size_t)(n0 + wcol) * NH + (size_t)kh * KSEG)
                      : (Wlq + (size_t)(n0 + wcol) * NL + (size_t)(kh - HSEG) * KSEG);
  const float* sbase = (hi ? sh + (size_t)kh * NT * OUT_DIM
                           : sl + (size_t)(kh - HSEG) * NT * OUT_DIM) + n0;
  const float* zbase = (hi ? zh + (size_t)kh * NT * OUT_DIM
                           : zl + (size_t)(kh - HSEG) * NT * OUT_DIM) + n0;

  // A base: row = wv*64 + i*16 + l15, k = kh*KSEG + s*BK + g4*8 (bf16x8)
  const unsigned short* xA = xp + (size_t)(wv * 64 + l15) * IN_DIM
                                + (size_t)kh * KSEG + g4 * 8;

  f32x4 acc[4][4];
  {
    float bvj[4];
    #pragma unroll
    for (int j = 0; j < 4; ++j)
      bvj[j] = (kh == 0) ? bias[n0 + j * 16 + l15] : 0.f;
    #pragma unroll
    for (int i = 0; i < 4; ++i)
      #pragma unroll
      for (int j = 0; j < 4; ++j) {
        acc[i][j][0] = bvj[j]; acc[i][j][1] = bvj[j];
        acc[i][j][2] = bvj[j]; acc[i][j][3] = bvj[j];
      }
  }

  auto aload = [&](bf16x8 (&af)[4], int s) {
    #pragma unroll
    for (int i = 0; i < 4; ++i)
      af[i] = *(const bf16x8*)(xA + (size_t)i * 16 * IN_DIM + s * BK);
  };
  auto wload = [&](int4& a, int4& b, int s) {
    const int* p = wb0 + s * BK + wm * 8;
    a = *(const int4*)p;
    b = *(const int4*)(p + 4);
  };
  auto wdeq = [&](int bx, int4 a, int4 b, int s) {   // dequant W(s) -> wlds[bx]
    int tl = s >> 2;
    float sc = *(const float*)(smem + SCOFF + (tl * 64 + wcol) * 4);
    float zs = *(const float*)(smem + ZSOFF + (tl * 64 + wcol) * 4);
    uint4 d;
    d.x = pk2((float)a.x * sc - zs, (float)a.y * sc - zs);
    d.y = pk2((float)a.z * sc - zs, (float)a.w * sc - zs);
    d.z = pk2((float)b.x * sc - zs, (float)b.y * sc - zs);
    d.w = pk2((float)b.z * sc - zs, (float)b.w * sc - zs);
    *(uint4*)(smem + WOFF + bx * 4096 + wcol * 64 + ((wm ^ (wcol & 3)) * 16)) = d;
  };
  auto compute = [&](int bx, const bf16x8 (&af)[4]) {
    const char* wbuf = smem + WOFF + bx * 4096;
    bf16x8 b[4];
    #pragma unroll
    for (int j = 0; j < 4; ++j) {
      int col = j * 16 + l15;
      int ch = g4 ^ (col & 3);
      b[j] = *(const bf16x8*)(wbuf + col * 64 + ch * 16);
    }
    #pragma unroll
    for (int i = 0; i < 4; ++i)
      #pragma unroll
      for (int j = 0; j < 4; ++j)
        acc[i][j] = __builtin_amdgcn_mfma_f32_16x16x32_bf16(af[i], b[j], acc[i][j], 0, 0, 0);
  };

  // ---- prologue: scales -> LDS, then pipeline prime (after the one full sync)
  #pragma unroll
  for (int r = 0; r < (NT * 64) / BDIM; ++r) {
    int p = t + r * BDIM;              // (tile,col): tile=p>>6, col=p&63
    float s_ = sbase[(size_t)(p >> 6) * OUT_DIM + (p & 63)];
    float z_ = zbase[(size_t)(p >> 6) * OUT_DIM + (p & 63)];
    *(float*)(smem + SCOFF + p * 4) = s_;
    *(float*)(smem + ZSOFF + p * 4) = z_ * s_;
  }
  __syncthreads();                     // scales visible (one-time full drain)

  bf16x8 afA[4], afB[4];
  int4 qa0, qa1, qb0, qb1;
  aload(afA, 0);
  wload(qa0, qa1, 0);
  wload(qb0, qb1, 1);
  wdeq(0, qa0, qa1, 0);                // compiler waits vmcnt for W(0) only
  asm volatile("s_waitcnt lgkmcnt(0)");
  __builtin_amdgcn_sched_barrier(0);
  __builtin_amdgcn_s_barrier();

  // ---- main loop: per step issue A(s+1), W(s+2); dequant W(s+1); MFMA(s).
  // Pre-barrier wait is lgkmcnt(0) only; prefetches stay in flight across it.
  #pragma unroll 1
  for (int it = 0; it < NSTEP / 2 - 1; ++it) {
    const int s = it * 2;
    // even step s: consume wlds[0], afA
    aload(afB, s + 1);
    wload(qa0, qa1, s + 2);
    __builtin_amdgcn_sched_barrier(0);
    wdeq(1, qb0, qb1, s + 1);
    compute(0, afA);
    asm volatile("s_waitcnt lgkmcnt(0)");
    __builtin_amdgcn_sched_barrier(0);
    __builtin_amdgcn_s_barrier();
    // odd step s+1: consume wlds[1], afB
    aload(afA, s + 2);
    wload(qb0, qb1, s + 3);
    __builtin_amdgcn_sched_barrier(0);
    wdeq(0, qa0, qa1, s + 2);
    compute(1, afB);
    asm volatile("s_waitcnt lgkmcnt(0)");
    __builtin_amdgcn_sched_barrier(0);
    __builtin_amdgcn_s_barrier();
  }
  // step NSTEP-2 (even): last A load, no more W loads
  aload(afB, NSTEP - 1);
  __builtin_amdgcn_sched_barrier(0);
  wdeq(1, qb0, qb1, NSTEP - 1);
  compute(0, afA);
  asm volatile("s_waitcnt lgkmcnt(0)");
  __builtin_amdgcn_sched_barrier(0);
  __builtin_amdgcn_s_barrier();
  // step NSTEP-1 (odd)
  compute(1, afB);

  // ---- epilogue: C/D mapping col=lane&15, row=(lane>>4)*4+reg
  if (use_atomic) {
    #pragma unroll
    for (int i = 0; i < 4; ++i) {
      int row0 = wv * 64 + i * 16 + g4 * 4;
      #pragma unroll
      for (int j = 0; j < 4; ++j) {
        int col = n0 + j * 16 + l15;
        #pragma unroll
        for (int r = 0; r < 4; ++r)
          atomicAdd(&outp[(size_t)(row0 + r) * OUT_DIM + col], acc[i][j][r]);
      }
    }
  } else {
    float* pp = outp + (size_t)kh * ((size_t)BDIM * OUT_DIM);
    #pragma unroll
    for (int i = 0; i < 4; ++i) {
      int row0 = wv * 64 + i * 16 + g4 * 4;
      #pragma unroll
      for (int j = 0; j < 4; ++j) {
        int col = n0 + j * 16 + l15;
        #pragma unroll
        for (int r = 0; r < 4; ++r)
          pp[(size_t)(row0 + r) * OUT_DIM + col] = acc[i][j][r];
      }
    }
  }
}

// ---------------- reduce: out = sum of NS partials (bias folded in kh=0) ---
template<int NS>
__global__ void reduce_k(const float* __restrict__ part,
                         float* __restrict__ out) {
  int i4 = blockIdx.x * blockDim.x + threadIdx.x;   // 0..524287
  size_t off = (size_t)i4 * 4;
  const size_t S = (size_t)BDIM * OUT_DIM;
  float4 r = *(const float4*)(part + off);
  #pragma unroll
  for (int k = 1; k < NS; ++k) {
    float4 p = *(const float4*)(part + off + (size_t)k * S);
    r.x += p.x; r.y += p.y; r.z += p.z; r.w += p.w;
  }
  *(float4*)(out + off) = r;
}

extern "C" void kernel_launch(void* const* d_in, const int* in_sizes, int n_in,
                              void* d_out, int out_size, void* d_ws, size_t ws_size,
                              hipStream_t stream) {
  const float* x   = (const float*)d_in[0];
  const int* Whq   = (const int*)d_in[1];
  const int* Wlq   = (const int*)d_in[2];
  const float* sh  = (const float*)d_in[3];
  const float* zh  = (const float*)d_in[4];
  const float* sl  = (const float*)d_in[5];
  const float* zl  = (const float*)d_in[6];
  const float* bias = (const float*)d_in[7];
  const int* ci    = (const int*)d_in[8];
  float* out = (float*)d_out;

  unsigned short* xp = (unsigned short*)d_ws;
  const size_t XP_BYTES = (size_t)BDIM * IN_DIM * 2;                  // 4MB
  const size_t SEG_BYTES = (size_t)BDIM * OUT_DIM * 4;                // 8MB
  bool ws8 = ws_size >= XP_BYTES + 8 * SEG_BYTES;                     // 68MB
  bool ws4 = ws_size >= XP_BYTES + 4 * SEG_BYTES;                     // 36MB

  gather_k<<<dim3(2048), dim3(256), 0, stream>>>(x, ci, xp);

  if (ws8) {
    float* part = (float*)((char*)d_ws + XP_BYTES);
    gemm_k<8><<<dim3(OUT_DIM / BN, 8), dim3(256), 0, stream>>>(
        xp, Whq, Wlq, sh, zh, sl, zl, bias, part, 0);
    reduce_k<8><<<dim3(2048), dim3(256), 0, stream>>>(part, out);
  } else if (ws4) {
    float* part = (float*)((char*)d_ws + XP_BYTES);
    gemm_k<4><<<dim3(OUT_DIM / BN, 4), dim3(256), 0, stream>>>(
        xp, Whq, Wlq, sh, zh, sl, zl, bias, part, 0);
    reduce_k<4><<<dim3(2048), dim3(256), 0, stream>>>(part, out);
  } else {
    hipMemsetAsync(d_out, 0, (size_t)out_size * sizeof(float), stream);
    gemm_k<4><<<dim3(OUT_DIM / BN, 4), dim3(256), 0, stream>>>(
        xp, Whq, Wlq, sh, zh, sl, zl, bias, out, 1);
  }
}